// Round 4
// baseline (626.089 us; speedup 1.0000x reference)
//
#include <hip/hip_runtime.h>
#include <math.h>

#define K_PROTO 65536
#define NV 5              // student views used per chunk
#define SVIEWS 6          // n_views+1 student rows per chunk
// base-2 domain: v_exp_f32 computes 2^x, so fold log2(e) into the temperature
#define TS2 14.4269504088896340736f   // (1/0.1)  * log2(e)
#define TT2 36.0673760222240851840f   // (1/0.04) * log2(e)
#define LN2 0.69314718055994530942f
#define NSLICE 16         // K-slices per chunk (one wave each)
#define SLICE (K_PROTO / NSLICE)          // 4096 columns per wave
#define BLOCK 256
#define WPB (BLOCK / 64)                  // 4 waves per block
#define ITERS (SLICE / (64 * 4))          // 16 half-KB steps per lane
#define PSTRIDE 24                        // floats per wave partial

typedef float floatx4 __attribute__((ext_vector_type(4)));

__device__ __forceinline__ floatx4 ld4(const float* p) {
    return *(const floatx4*)p;
}
__device__ __forceinline__ float fexp2(float x) { return __builtin_amdgcn_exp2f(x); }
__device__ __forceinline__ float flog2(float x) { return __builtin_amdgcn_logf(x); }

// Streaming kernel: one wave per (chunk, K-slice). No LDS, no barriers,
// regular (L2-cached) loads, ping-pong double buffer with NO register copies
// so the compiler can emit partial vmcnt waits. All softmax math in base-2;
// the uniform 2^-m scaling cancels in D/Z and is exact in LSE.
__global__ __launch_bounds__(BLOCK) void dino_partial(
    const float* __restrict__ vs,
    const float* __restrict__ vt,
    const float* __restrict__ center,
    float* __restrict__ ws)
{
    const int w    = blockIdx.x * WPB + (threadIdx.x >> 6);
    const int lane = threadIdx.x & 63;
    const int c    = w >> 4;              // chunk index
    const int s    = w & (NSLICE - 1);    // K-slice index
    const int kb   = s * SLICE + lane * 4;

    const float* rp[8];
    rp[0] = center + kb;
    rp[1] = vt + (size_t)(2 * c + 0) * K_PROTO + kb;
    rp[2] = vt + (size_t)(2 * c + 1) * K_PROTO + kb;
#pragma unroll
    for (int j = 0; j < NV; ++j)
        rp[3 + j] = vs + (size_t)(SVIEWS * c + j) * K_PROTO + kb;

    // online-softmax state (base-2 domain)
    float tm[2] = {-INFINITY, -INFINITY};
    float tZ[2] = {0.f, 0.f};
    float D[2][NV];
    float sm[NV], sZ[NV];
#pragma unroll
    for (int i = 0; i < 2; ++i)
#pragma unroll
        for (int j = 0; j < NV; ++j) D[i][j] = 0.f;
#pragma unroll
    for (int j = 0; j < NV; ++j) { sm[j] = -INFINITY; sZ[j] = 0.f; }

    floatx4 A[8], B[8];

    auto loadg = [&](floatx4* buf, int off) {
#pragma unroll
        for (int r = 0; r < 8; ++r) buf[r] = ld4(rp[r] + off);
    };

    auto compute = [&](const floatx4* buf) {
        // ---- students: xs2 = vs * (10*log2e), online base-2 LSE
        float xs[NV][4];
#pragma unroll
        for (int j = 0; j < NV; ++j) {
            const floatx4 sv = buf[3 + j];
            xs[j][0] = fmaf(sv.x, TS2, 1.4426950e-20f);
            xs[j][1] = fmaf(sv.y, TS2, 1.4426950e-20f);
            xs[j][2] = fmaf(sv.z, TS2, 1.4426950e-20f);
            xs[j][3] = fmaf(sv.w, TS2, 1.4426950e-20f);
            float m4 = fmaxf(fmaxf(xs[j][0], xs[j][1]), fmaxf(xs[j][2], xs[j][3]));
            float mn = fmaxf(sm[j], m4);
            float r  = fexp2(sm[j] - mn);
            float p0 = fexp2(xs[j][0] - mn);
            float p1 = fexp2(xs[j][1] - mn);
            float p2 = fexp2(xs[j][2] - mn);
            float p3 = fexp2(xs[j][3] - mn);
            sZ[j] = fmaf(sZ[j], r, (p0 + p1) + (p2 + p3));
            sm[j] = mn;
        }

        // ---- teachers: x2 = (vt-center) * (25*log2e)
        const floatx4 c4 = buf[0];
        const float cc0 = c4.x * TT2, cc1 = c4.y * TT2;
        const float cc2 = c4.z * TT2, cc3 = c4.w * TT2;
#pragma unroll
        for (int i = 0; i < 2; ++i) {
            const floatx4 tv = buf[1 + i];
            float x0 = fmaf(tv.x, TT2, -cc0);
            float x1 = fmaf(tv.y, TT2, -cc1);
            float x2 = fmaf(tv.z, TT2, -cc2);
            float x3 = fmaf(tv.w, TT2, -cc3);
            float m4 = fmaxf(fmaxf(x0, x1), fmaxf(x2, x3));
            float mn = fmaxf(tm[i], m4);
            float r  = fexp2(tm[i] - mn);
            float p0 = fexp2(x0 - mn);
            float p1 = fexp2(x1 - mn);
            float p2 = fexp2(x2 - mn);
            float p3 = fexp2(x3 - mn);
            tZ[i] = fmaf(tZ[i], r, (p0 + p1) + (p2 + p3));
#pragma unroll
            for (int j = 0; j < NV; ++j) {
                float acc = fmaf(p0, xs[j][0],
                            fmaf(p1, xs[j][1],
                            fmaf(p2, xs[j][2], p3 * xs[j][3])));
                D[i][j] = fmaf(D[i][j], r, acc);
            }
            tm[i] = mn;
        }
    };

    // ping-pong pipeline: no buffer copies -> partial vmcnt waits
    loadg(A, 0);
    loadg(B, 256);
#pragma unroll
    for (int it = 0; it < ITERS; it += 2) {
        compute(A);
        if (it + 2 < ITERS) loadg(A, (it + 2) * 256);
        compute(B);
        if (it + 3 < ITERS) loadg(B, (it + 3) * 256);
    }

    // ---- 64-lane butterfly merge (base-2 rescales)
#pragma unroll
    for (int off = 32; off >= 1; off >>= 1) {
#pragma unroll
        for (int i = 0; i < 2; ++i) {
            float om = __shfl_xor(tm[i], off);
            float oZ = __shfl_xor(tZ[i], off);
            float oD[NV];
#pragma unroll
            for (int j = 0; j < NV; ++j) oD[j] = __shfl_xor(D[i][j], off);
            float mn = fmaxf(tm[i], om);
            float a  = fexp2(tm[i] - mn);
            float b  = fexp2(om - mn);
            tZ[i] = tZ[i] * a + oZ * b;
#pragma unroll
            for (int j = 0; j < NV; ++j) D[i][j] = D[i][j] * a + oD[j] * b;
            tm[i] = mn;
        }
#pragma unroll
        for (int j = 0; j < NV; ++j) {
            float om = __shfl_xor(sm[j], off);
            float oZ = __shfl_xor(sZ[j], off);
            float mn = fmaxf(sm[j], om);
            sZ[j] = sZ[j] * fexp2(sm[j] - mn) + oZ * fexp2(om - mn);
            sm[j] = mn;
        }
    }

    if (lane == 0) {
        float* p = ws + (size_t)w * PSTRIDE;
        p[0] = tm[0]; p[1] = tm[1]; p[2] = tZ[0]; p[3] = tZ[1];
#pragma unroll
        for (int i = 0; i < 2; ++i)
#pragma unroll
            for (int j = 0; j < NV; ++j) p[4 + i * NV + j] = D[i][j];
#pragma unroll
        for (int j = 0; j < NV; ++j) { p[14 + j] = sm[j]; p[19 + j] = sZ[j]; }
    }
}

// Single-block finalize: merge NSLICE partials per chunk (base-2), sum,
// write out[0].  lse_ln = (m2 + log2(Z)) * ln2;  cross term = lse - D/Z.
__global__ __launch_bounds__(256) void dino_finalize(
    const float* __restrict__ ws, float* __restrict__ out,
    int n, float inv_count)
{
    const int t = threadIdx.x;
    float local = 0.f;

    for (int c = t; c < n; c += 256) {
        const float* p = ws + (size_t)c * NSLICE * PSTRIDE;
        float gm[2], gZ[2], gD[2][NV], gsm[NV], gsZ[NV];
        gm[0] = p[0]; gm[1] = p[1]; gZ[0] = p[2]; gZ[1] = p[3];
#pragma unroll
        for (int i = 0; i < 2; ++i)
#pragma unroll
            for (int j = 0; j < NV; ++j) gD[i][j] = p[4 + i * NV + j];
#pragma unroll
        for (int j = 0; j < NV; ++j) { gsm[j] = p[14 + j]; gsZ[j] = p[19 + j]; }

        for (int s2 = 1; s2 < NSLICE; ++s2) {
            const float* q = p + s2 * PSTRIDE;
#pragma unroll
            for (int i = 0; i < 2; ++i) {
                float om = q[i], oZ = q[2 + i];
                float mn = fmaxf(gm[i], om);
                float a = fexp2(gm[i] - mn), b = fexp2(om - mn);
                gZ[i] = gZ[i] * a + oZ * b;
#pragma unroll
                for (int j = 0; j < NV; ++j)
                    gD[i][j] = gD[i][j] * a + q[4 + i * NV + j] * b;
                gm[i] = mn;
            }
#pragma unroll
            for (int j = 0; j < NV; ++j) {
                float om = q[14 + j], oZ = q[19 + j];
                float mn = fmaxf(gsm[j], om);
                gsZ[j] = gsZ[j] * fexp2(gsm[j] - mn) + oZ * fexp2(om - mn);
                gsm[j] = mn;
            }
        }

        float sum = 0.f;
#pragma unroll
        for (int j = 0; j < NV; ++j) {
            float lse = (gsm[j] + flog2(gsZ[j])) * LN2;
#pragma unroll
            for (int i = 0; i < 2; ++i)
                sum += lse - gD[i][j] / gZ[i];
        }
        local += sum;
    }

    // block-wide sum (4 waves)
#pragma unroll
    for (int off = 32; off >= 1; off >>= 1) local += __shfl_xor(local, off);
    __shared__ float red[4];
    if ((t & 63) == 0) red[t >> 6] = local;
    __syncthreads();
    if (t == 0) out[0] = (red[0] + red[1] + red[2] + red[3]) * inv_count;
}

extern "C" void kernel_launch(void* const* d_in, const int* in_sizes, int n_in,
                              void* d_out, int out_size, void* d_ws, size_t ws_size,
                              hipStream_t stream) {
    const float* vs     = (const float*)d_in[0];
    const float* vt     = (const float*)d_in[1];
    const float* center = (const float*)d_in[2];
    float* out = (float*)d_out;
    float* ws  = (float*)d_ws;

    const int S = in_sizes[0] / K_PROTO;   // 1536
    const int T = in_sizes[1] / K_PROTO;   // 512
    int n = S / SVIEWS;
    if (T / 2 < n) n = T / 2;              // 256

    if (n > 0) {
        const int nblocks = n * NSLICE / WPB;   // 1024
        dino_partial<<<nblocks, BLOCK, 0, stream>>>(vs, vt, center, ws);
        dino_finalize<<<1, 256, 0, stream>>>(ws, out, n, 1.0f / (float)(n * 2 * NV));
    }
}

// Round 5
// 562.884 us; speedup vs baseline: 1.1123x; 1.1123x over previous
//
#include <hip/hip_runtime.h>
#include <math.h>

#define K_PROTO 65536
#define NV 5              // student views used per chunk
#define SVIEWS 6          // n_views+1 student rows per chunk
// base-2 domain: v_exp_f32 computes 2^x, fold log2(e) into the temperatures
#define TS2 14.4269504088896340736f   // (1/0.1)  * log2(e)
#define TT2 36.0673760222240851840f   // (1/0.04) * log2(e)
#define EPS2 1.4426950408889634e-20f  // 1e-20 * log2(e)
#define LN2 0.69314718055994530942f
#define NSLICE 16         // K-slices per chunk (one wave each)
#define SLICE (K_PROTO / NSLICE)          // 4096 columns per wave
#define BLOCK 256
#define WPB (BLOCK / 64)                  // 4 waves per block
#define ITERS (SLICE / (64 * 4))          // 16 half-KB steps per lane
#define PSTRIDE 20                        // floats per wave partial

typedef float floatx4 __attribute__((ext_vector_type(4)));

__device__ __forceinline__ floatx4 ntload4(const float* p) {
    return __builtin_nontemporal_load((const floatx4*)p);
}
__device__ __forceinline__ floatx4 ld4(const float* p) {
    return *(const floatx4*)p;
}
__device__ __forceinline__ float fexp2(float x) { return __builtin_amdgcn_exp2f(x); }
__device__ __forceinline__ float flog2(float x) { return __builtin_amdgcn_logf(x); }

// One wave per (chunk, K-slice). No LDS/barriers. Rolled (NOT unrolled)
// ping-pong double buffer: no register copies, so the compiler can wait on
// half the outstanding loads (partial vmcnt) while the other 8 stay in
// flight. Students use max-free base-2 sum-of-exp2 (exact: 2^x can't
// overflow for |vs|*10*log2e < ~90); teacher keeps online-max (x25 would
// overflow). D[i][j] = sum_k 2^(xt2[i,k]-m_i) * xs2[j,k]; the final *ln2
// converts student log-probs back to the natural-log domain.
__global__ __launch_bounds__(BLOCK) void dino_partial(
    const float* __restrict__ vs,
    const float* __restrict__ vt,
    const float* __restrict__ center,
    float* __restrict__ ws)
{
    const int w    = blockIdx.x * WPB + (threadIdx.x >> 6);
    const int lane = threadIdx.x & 63;
    const int c    = w >> 4;              // chunk index
    const int s    = w & (NSLICE - 1);    // K-slice index
    const int kb   = s * SLICE + lane * 4;

    const float* rp[8];
    rp[0] = center + kb;
    rp[1] = vt + (size_t)(2 * c + 0) * K_PROTO + kb;
    rp[2] = vt + (size_t)(2 * c + 1) * K_PROTO + kb;
#pragma unroll
    for (int j = 0; j < NV; ++j)
        rp[3 + j] = vs + (size_t)(SVIEWS * c + j) * K_PROTO + kb;

    float tm[2] = {-INFINITY, -INFINITY};   // teacher running max (base-2)
    float tZ[2] = {0.f, 0.f};               // teacher running sum 2^(x-m)
    float D[2][NV];
    float sZ[NV];                           // student plain sum of 2^xs2
#pragma unroll
    for (int i = 0; i < 2; ++i)
#pragma unroll
        for (int j = 0; j < NV; ++j) D[i][j] = 0.f;
#pragma unroll
    for (int j = 0; j < NV; ++j) sZ[j] = 0.f;

    floatx4 A[8], B[8];

    auto loadg = [&](floatx4* buf, int off) {
        buf[0] = ld4(rp[0] + off);          // center: L2-reused across waves
#pragma unroll
        for (int r = 1; r < 8; ++r) buf[r] = ntload4(rp[r] + off);
    };

    auto compute = [&](const floatx4* buf) {
        // ---- students: xs2 = vs*(10*log2e)+eps2, max-free sum of 2^xs2
        float xs[NV][4];
#pragma unroll
        for (int j = 0; j < NV; ++j) {
            const floatx4 sv = buf[3 + j];
            xs[j][0] = fmaf(sv.x, TS2, EPS2);
            xs[j][1] = fmaf(sv.y, TS2, EPS2);
            xs[j][2] = fmaf(sv.z, TS2, EPS2);
            xs[j][3] = fmaf(sv.w, TS2, EPS2);
            float e0 = fexp2(xs[j][0]);
            float e1 = fexp2(xs[j][1]);
            float e2 = fexp2(xs[j][2]);
            float e3 = fexp2(xs[j][3]);
            sZ[j] += (e0 + e1) + (e2 + e3);
        }

        // ---- teachers: x2 = (vt-center)*(25*log2e), online base-2 softmax
        const floatx4 c4 = buf[0];
        const float cc0 = c4.x * TT2, cc1 = c4.y * TT2;
        const float cc2 = c4.z * TT2, cc3 = c4.w * TT2;
#pragma unroll
        for (int i = 0; i < 2; ++i) {
            const floatx4 tv = buf[1 + i];
            float x0 = fmaf(tv.x, TT2, -cc0);
            float x1 = fmaf(tv.y, TT2, -cc1);
            float x2 = fmaf(tv.z, TT2, -cc2);
            float x3 = fmaf(tv.w, TT2, -cc3);
            float m4 = fmaxf(fmaxf(x0, x1), fmaxf(x2, x3));
            float mn = fmaxf(tm[i], m4);
            float r  = fexp2(tm[i] - mn);
            float p0 = fexp2(x0 - mn);
            float p1 = fexp2(x1 - mn);
            float p2 = fexp2(x2 - mn);
            float p3 = fexp2(x3 - mn);
            tZ[i] = fmaf(tZ[i], r, (p0 + p1) + (p2 + p3));
#pragma unroll
            for (int j = 0; j < NV; ++j) {
                float acc = fmaf(p0, xs[j][0],
                            fmaf(p1, xs[j][1],
                            fmaf(p2, xs[j][2], p3 * xs[j][3])));
                D[i][j] = fmaf(D[i][j], r, acc);
            }
            tm[i] = mn;
        }
    };

    // rolled ping-pong: each compute waits only on its own 8 loads while the
    // other buffer's 8 stay in flight. Keep the loop ROLLED (R4's full unroll
    // made a ~29 KB body -> I-cache thrash).
    loadg(A, 0);
    loadg(B, 256);
#pragma unroll 1
    for (int it = 0; it < ITERS; it += 2) {
        compute(A);
        if (it + 2 < ITERS) loadg(A, (it + 2) * 256);
        compute(B);
        if (it + 3 < ITERS) loadg(B, (it + 3) * 256);
    }

    // ---- 64-lane butterfly merge
#pragma unroll
    for (int off = 32; off >= 1; off >>= 1) {
#pragma unroll
        for (int i = 0; i < 2; ++i) {
            float om = __shfl_xor(tm[i], off);
            float oZ = __shfl_xor(tZ[i], off);
            float oD[NV];
#pragma unroll
            for (int j = 0; j < NV; ++j) oD[j] = __shfl_xor(D[i][j], off);
            float mn = fmaxf(tm[i], om);
            float a  = fexp2(tm[i] - mn);
            float b  = fexp2(om - mn);
            tZ[i] = tZ[i] * a + oZ * b;
#pragma unroll
            for (int j = 0; j < NV; ++j) D[i][j] = D[i][j] * a + oD[j] * b;
            tm[i] = mn;
        }
#pragma unroll
        for (int j = 0; j < NV; ++j) sZ[j] += __shfl_xor(sZ[j], off);
    }

    if (lane == 0) {
        float* p = ws + (size_t)w * PSTRIDE;
        p[0] = tm[0]; p[1] = tm[1]; p[2] = tZ[0]; p[3] = tZ[1];
#pragma unroll
        for (int i = 0; i < 2; ++i)
#pragma unroll
            for (int j = 0; j < NV; ++j) p[4 + i * NV + j] = D[i][j];
#pragma unroll
        for (int j = 0; j < NV; ++j) p[14 + j] = sZ[j];
    }
}

// Single-block finalize: merge NSLICE partials per chunk, sum, write out[0].
// term(b2) = log2(sum sZ) - D/Z ; loss = (sum terms) * ln2 / count.
__global__ __launch_bounds__(256) void dino_finalize(
    const float* __restrict__ ws, float* __restrict__ out,
    int n, float scale)
{
    const int t = threadIdx.x;
    float local = 0.f;

    for (int c = t; c < n; c += 256) {
        const float* p = ws + (size_t)c * NSLICE * PSTRIDE;
        float gm[2], gZ[2], gD[2][NV], gsZ[NV];
        gm[0] = p[0]; gm[1] = p[1]; gZ[0] = p[2]; gZ[1] = p[3];
#pragma unroll
        for (int i = 0; i < 2; ++i)
#pragma unroll
            for (int j = 0; j < NV; ++j) gD[i][j] = p[4 + i * NV + j];
#pragma unroll
        for (int j = 0; j < NV; ++j) gsZ[j] = p[14 + j];

        for (int s2 = 1; s2 < NSLICE; ++s2) {
            const float* q = p + s2 * PSTRIDE;
#pragma unroll
            for (int i = 0; i < 2; ++i) {
                float om = q[i], oZ = q[2 + i];
                float mn = fmaxf(gm[i], om);
                float a = fexp2(gm[i] - mn), b = fexp2(om - mn);
                gZ[i] = gZ[i] * a + oZ * b;
#pragma unroll
                for (int j = 0; j < NV; ++j)
                    gD[i][j] = gD[i][j] * a + q[4 + i * NV + j] * b;
                gm[i] = mn;
            }
#pragma unroll
            for (int j = 0; j < NV; ++j) gsZ[j] += q[14 + j];
        }

        float sum = 0.f;
#pragma unroll
        for (int j = 0; j < NV; ++j) {
            float lse2 = flog2(gsZ[j]);
#pragma unroll
            for (int i = 0; i < 2; ++i)
                sum += lse2 - gD[i][j] / gZ[i];
        }
        local += sum;
    }

#pragma unroll
    for (int off = 32; off >= 1; off >>= 1) local += __shfl_xor(local, off);
    __shared__ float red[4];
    if ((t & 63) == 0) red[t >> 6] = local;
    __syncthreads();
    if (t == 0) out[0] = (red[0] + red[1] + red[2] + red[3]) * scale;
}

extern "C" void kernel_launch(void* const* d_in, const int* in_sizes, int n_in,
                              void* d_out, int out_size, void* d_ws, size_t ws_size,
                              hipStream_t stream) {
    const float* vs     = (const float*)d_in[0];
    const float* vt     = (const float*)d_in[1];
    const float* center = (const float*)d_in[2];
    float* out = (float*)d_out;
    float* ws  = (float*)d_ws;

    const int S = in_sizes[0] / K_PROTO;   // 1536
    const int T = in_sizes[1] / K_PROTO;   // 512
    int n = S / SVIEWS;
    if (T / 2 < n) n = T / 2;              // 256

    if (n > 0) {
        const int nblocks = n * NSLICE / WPB;   // 1024
        const float scale = LN2 / (float)(n * 2 * NV);
        dino_partial<<<nblocks, BLOCK, 0, stream>>>(vs, vt, center, ws);
        dino_finalize<<<1, 256, 0, stream>>>(ws, out, n, scale);
    }
}